// Round 10
// baseline (296.766 us; speedup 1.0000x reference)
//
#include <hip/hip_runtime.h>

#define NODE 100
#define BATCH 64
#define DIM 128
#define IN_DIM 5
#define TOPK 30
#define INTER 256
#define NB (BATCH*NODE)   /* 6400 */
#define EPS 1e-5f
#define SLOPE 0.2f
#define REP 16
#define NBLK 400          /* block b owns rows [16b,16b+16) */
#define ROWS 16
#define NTHR 512
#define GRPS 16
#define GRPSZ (NBLK/GRPS) /* 25 */

// ws float offsets — ONLY stats + barriers live in global scratch now
#define OFF_STATA 0        /* REP*32  */
#define OFF_STAT2 512      /* REP*256 */
#define OFF_STAT3 4608     /* REP*512 */
#define OFF_BARF  12800    /* 3 barriers x 4096 ints */
#define BAR_STRIDE 4096
#define ZERO_BYTES ((OFF_BARF + 3*BAR_STRIDE) * 4)

// LDS regions (floats). Total 18944 fl = 75776 B -> 2 blocks/CU (<=80KB).
// R0 [0,12800):   A/B: eT[128][100]   C: wT[32][260]@0, ps[8][256]@8320, ps2@10368   D: raw@0,mu3@512,rs3@768
// R1 [12800,14848): aggL/x3 [16][128] (in-place rewrites)
// R2 [14848,18944): A: scratch        B: pv@0,pq@512,A20@1024   C1: bn2raw@0,mu2@256,rs2@384   C3/D: o1L[16][256]
#define R1_OFF 12800
#define R2_OFF 14848
#define SMEM_FL 18944

__device__ __forceinline__ float aload(const float* p) {
    return __hip_atomic_load(p, __ATOMIC_RELAXED, __HIP_MEMORY_SCOPE_AGENT);
}

// hierarchical grid barrier: spread arrive lines; members poll per-group flag,
// only 16 leaders poll the root flag. release/acquire, no cache-wide fences.
__device__ __forceinline__ void gbar(int* base) {
    __syncthreads();
    if (threadIdx.x == 0) {
        int g = blockIdx.x & (GRPS-1);
        int* sub   = base + g*64;
        int* root  = base + 1024;
        int* rflag = base + 1088;
        int* gflag = base + 2048 + g*64;
        int v = __hip_atomic_fetch_add(sub, 1, __ATOMIC_RELEASE, __HIP_MEMORY_SCOPE_AGENT);
        if (v == GRPSZ-1) {
            int r = __hip_atomic_fetch_add(root, 1, __ATOMIC_ACQ_REL, __HIP_MEMORY_SCOPE_AGENT);
            if (r == GRPS-1) {
                __hip_atomic_store(rflag, 1, __ATOMIC_RELEASE, __HIP_MEMORY_SCOPE_AGENT);
            } else {
                while (!__hip_atomic_load(rflag, __ATOMIC_ACQUIRE, __HIP_MEMORY_SCOPE_AGENT))
                    __builtin_amdgcn_s_sleep(4);
            }
            __hip_atomic_store(gflag, 1, __ATOMIC_RELEASE, __HIP_MEMORY_SCOPE_AGENT);
        } else {
            while (!__hip_atomic_load(gflag, __ATOMIC_ACQUIRE, __HIP_MEMORY_SCOPE_AGENT))
                __builtin_amdgcn_s_sleep(4);
        }
    }
    __syncthreads();
}

__global__ __launch_bounds__(NTHR, 4) void k_fused(
        const float* __restrict__ x, const float* __restrict__ emb,
        const float* __restrict__ w_lin,
        const float* __restrict__ att_i, const float* __restrict__ att_j,
        const float* __restrict__ att_em_i, const float* __restrict__ att_em_j,
        const float* __restrict__ g_bias,
        const float* __restrict__ g1, const float* __restrict__ b1,
        const float* __restrict__ g2, const float* __restrict__ b2v,
        const float* __restrict__ g3, const float* __restrict__ b3,
        const float* __restrict__ w1, const float* __restrict__ b1v,
        const float* __restrict__ w2, const float* __restrict__ b2s,
        float* __restrict__ ws, float* __restrict__ out) {
    __shared__ __align__(16) float smem[SMEM_FL];
    int* bar = (int*)(ws + OFF_BARF);
    const int b = blockIdx.x, t = threadIdx.x, w = t >> 6, l = t & 63;
    const float invn = 1.f/(float)NB;
    const int r0 = b * ROWS;
    const int fb = r0 / NODE, lb = (r0 + ROWS - 1) / NODE;
    float* eT   = smem;                 // [128][100]: eT[d*100+node]
    float* aggL = smem + R1_OFF;        // [16][128]
    // phase-A scratch in R2:
    float* xl   = smem + R2_OFF;        // [2][500]
    float* ej   = smem + R2_OFF + 1008; // [100]
    float* nrm  = smem + R2_OFF + 1112; // [100]
    float* sjl  = smem + R2_OFF + 1216; // [2][100]
    float* eiL  = smem + R2_OFF + 1424; // [16]
    float* uL   = smem + R2_OFF + 1440; // [10]
    float* psum = smem + R2_OFF + 1456; // [8][20]
    int*   idl  = (int*)(smem + R2_OFF + 1616); // [16][30]
    float* cosL = smem + R2_OFF + 2112; // [16][101]

    // ================= phase A: per-block topk + scalars + agg + statA =====
    // A1: load eT (coalesced global, scattered LDS), xl slabs, u vectors
    for (int i = t; i < NODE*DIM; i += NTHR) {
        int node = i >> 7, d = i & 127;
        eT[d*NODE + node] = emb[i];
    }
    for (int i = t; i < 500; i += NTHR) {
        xl[i]       = x[fb*500 + i];
        xl[500 + i] = x[lb*500 + i];
    }
    if (t < 10) {
        int c = (t < 5) ? t : t - 5;
        const float* P = (t < 5) ? att_i : att_j;
        float s = 0.f;
        for (int k = 0; k < DIM; ++k) s += w_lin[k*IN_DIM + c] * P[k];
        uL[t] = s;
    }
    __syncthreads();
    // A2: norms + ej (all nodes) + ei (owned nodes)
    if (t < NODE) {
        float sn = 0.f, se = 0.f;
        for (int d = 0; d < DIM; ++d) {
            float v = eT[d*NODE + t];
            sn += v*v;
            se += v * att_em_j[d];
        }
        nrm[t] = sn;
        ej[t] = se;
    } else if (t >= 128 && t < 128 + ROWS) {
        int node = (r0 + t - 128) % NODE;
        float s = 0.f;
        for (int d = 0; d < DIM; ++d) s += eT[d*NODE + node] * att_em_i[d];
        eiL[t - 128] = s;
    }
    __syncthreads();
    // A3: sjl + cosine pairs
    if (t < 200) {
        int bb = t / 100, n = t % 100;
        float s = ej[n];
#pragma unroll
        for (int c = 0; c < IN_DIM; ++c) s += xl[bb*500 + n*IN_DIM + c] * uL[5 + c];
        sjl[t] = s;
    }
    for (int p = t; p < ROWS*NODE; p += NTHR) {
        int ri = p / NODE, j = p % NODE;
        int ni = (r0 + ri) % NODE;
        float dot = 0.f;
        for (int d = 0; d < DIM; ++d) dot += eT[d*NODE + ni] * eT[d*NODE + j];
        cosL[ri*101 + j] = dot / (sqrtf(nrm[ni]) * sqrtf(nrm[j]));
    }
    __syncthreads();
    // A4: top-30 per owned row (wave w handles rows 2w, 2w+1)
    for (int rr = w*2; rr < w*2 + 2; ++rr) {
        float c0 = cosL[rr*101 + l];
        float c1 = (l < NODE - 64) ? cosL[rr*101 + 64 + l] : -INFINITY;
        int j0 = l, j1 = 64 + l;
        for (int r = 0; r < TOPK; ++r) {
            float bv; int bi;
            if (c1 > c0) { bv = c1; bi = j1; } else { bv = c0; bi = j0; }
#pragma unroll
            for (int m = 32; m >= 1; m >>= 1) {
                float ov = __shfl_xor(bv, m, 64);
                int   oi = __shfl_xor(bi, m, 64);
                if (ov > bv || (ov == bv && oi < bi)) { bv = ov; bi = oi; }
            }
            if (l == 0) idl[rr*TOPK + r] = bi;
            if (bi == j0) c0 = -INFINITY;
            if (bi == j1) c1 = -INFINITY;
        }
    }
    __syncthreads();
    // A5: attention agg in 5-dim space -> aggL + bn1 moment sums
    {
        float wl0[IN_DIM], wl1[IN_DIM];
#pragma unroll
        for (int c = 0; c < IN_DIM; ++c) {
            wl0[c] = w_lin[l*IN_DIM + c];
            wl1[c] = w_lin[(l+64)*IN_DIM + c];
        }
        float gb0 = g_bias[l], gb1 = g_bias[l+64];
        float S0=0,S1=0,S2=0,S3=0,S4=0;
        float M[15];
#pragma unroll
        for (int m = 0; m < 15; ++m) M[m] = 0.f;
        for (int rr = w; rr < ROWS; rr += 8) {
            int row = r0 + rr;
            int bb = (row / NODE == fb) ? 0 : 1;
            int node = row % NODE;
            float si = eiL[rr];
#pragma unroll
            for (int c = 0; c < IN_DIM; ++c) si += xl[bb*500 + node*IN_DIM + c] * uL[c];
            float mx = -INFINITY;
#pragma unroll
            for (int r = 0; r < TOPK; ++r) {
                int s = idl[rr*TOPK + r];
                float a = si + sjl[bb*100 + s];
                a = (a > 0.f) ? a : SLOPE*a;
                mx = fmaxf(mx, a);
            }
            float ssum = 0.f, x0=0,x1=0,x2=0,x3v=0,x4=0;
#pragma unroll
            for (int r = 0; r < TOPK; ++r) {
                int s = idl[rr*TOPK + r];
                float a = si + sjl[bb*100 + s];
                a = (a > 0.f) ? a : SLOPE*a;
                float e = expf(a - mx);
                ssum += e;
                const float* xr = &xl[bb*500 + s*IN_DIM];
                x0 += e*xr[0]; x1 += e*xr[1]; x2 += e*xr[2]; x3v += e*xr[3]; x4 += e*xr[4];
            }
            float inv = 1.f/(ssum + 1e-16f);
            float y0=x0*inv, y1=x1*inv, y2=x2*inv, y3=x3v*inv, y4=x4*inv;
            aggL[rr*DIM + l]      = y0*wl0[0]+y1*wl0[1]+y2*wl0[2]+y3*wl0[3]+y4*wl0[4] + gb0;
            aggL[rr*DIM + l + 64] = y0*wl1[0]+y1*wl1[1]+y2*wl1[2]+y3*wl1[3]+y4*wl1[4] + gb1;
            S0+=y0; S1+=y1; S2+=y2; S3+=y3; S4+=y4;
            M[0]+=y0*y0; M[1]+=y0*y1; M[2]+=y0*y2; M[3]+=y0*y3; M[4]+=y0*y4;
            M[5]+=y1*y1; M[6]+=y1*y2; M[7]+=y1*y3; M[8]+=y1*y4;
            M[9]+=y2*y2; M[10]+=y2*y3; M[11]+=y2*y4;
            M[12]+=y3*y3; M[13]+=y3*y4; M[14]+=y4*y4;
        }
        __syncthreads();
        if (l == 0) {
            psum[w*20+0]=S0; psum[w*20+1]=S1; psum[w*20+2]=S2; psum[w*20+3]=S3; psum[w*20+4]=S4;
#pragma unroll
            for (int m = 0; m < 15; ++m) psum[w*20+5+m] = M[m];
        }
        __syncthreads();
        if (t < 20) {
            float p = 0.f;
#pragma unroll
            for (int q = 0; q < 8; ++q) p += psum[q*20 + t];
            atomicAdd(&ws[OFF_STATA + (b & (REP-1))*32 + t], p);
        }
    }
    gbar(bar);

    // ================= phase B: x3 = relu(bn1(agg))*emb (in-place) + stat2 =
    {
        float* pv  = smem + R2_OFF;          // [4][128]
        float* pq  = smem + R2_OFF + 512;    // [4][128]
        float* A20 = smem + R2_OFF + 1024;   // [20]
        if (t < 20) {
            float s = 0.f;
#pragma unroll
            for (int r = 0; r < REP; ++r) s += aload(ws + OFF_STATA + r*32 + t);
            A20[t] = s;
        }
        __syncthreads();
        int c = t & 127;
        float w0 = w_lin[c*IN_DIM+0], w1v = w_lin[c*IN_DIM+1], w2v = w_lin[c*IN_DIM+2],
              w3 = w_lin[c*IN_DIM+3], w4 = w_lin[c*IN_DIM+4];
        float Sv = A20[0]*w0 + A20[1]*w1v + A20[2]*w2v + A20[3]*w3 + A20[4]*w4;
        float Q  = w0*w0*A20[5] + w1v*w1v*A20[10] + w2v*w2v*A20[14] + w3*w3*A20[17] + w4*w4*A20[19]
                 + 2.f*(w0*w1v*A20[6] + w0*w2v*A20[7] + w0*w3*A20[8] + w0*w4*A20[9]
                      + w1v*w2v*A20[11] + w1v*w3*A20[12] + w1v*w4*A20[13]
                      + w2v*w3*A20[15] + w2v*w4*A20[16] + w3*w4*A20[18]);
        float mv = Sv*invn;
        float mu = mv + g_bias[c];
        float var = fmaxf(Q*invn - mv*mv, 0.f);
        float rsg = rsqrtf(var + EPS) * g1[c];
        float bq = b1[c];
        float s1 = 0.f, s2 = 0.f;
#pragma unroll
        for (int k = 0; k < 4; ++k) {
            int e = t + k*NTHR;
            int row = e >> 7;
            int node = (r0 + row) % NODE;
            float val = (aggL[e] - mu)*rsg + bq;
            val = fmaxf(val, 0.f);
            float x3v = val * eT[c*NODE + node];
            aggL[e] = x3v;                      // in-place: same thread, same elem
            s1 += x3v; s2 += x3v*x3v;
        }
        pv[(t>>7)*128 + c] = s1;
        pq[(t>>7)*128 + c] = s2;
        __syncthreads();
        if (t < DIM) {
            float a1 = pv[t] + pv[128+t] + pv[256+t] + pv[384+t];
            float a2 = pq[t] + pq[128+t] + pq[256+t] + pq[384+t];
            atomicAdd(&ws[OFF_STAT2 + (b & (REP-1))*256 + t], a1);
            atomicAdd(&ws[OFF_STAT2 + (b & (REP-1))*256 + DIM + t], a2);
        }
    }
    gbar(bar + BAR_STRIDE);

    // ================= phase C: o1 = relu(bn2(x3)) @ w1^T + b1 + stat3 =====
    {
        float* bn2raw = smem + R2_OFF;        // 256
        float* mu2l   = smem + R2_OFF + 256;  // 128
        float* rs2l   = smem + R2_OFF + 384;  // 128
        float* wT     = smem;                 // [32][260]
        float* ps     = smem + 8320;          // [8][256]
        float* ps2    = smem + 10368;         // [8][256]
        float* o1L    = smem + R2_OFF;        // [16][256] (after mu2l dead)
        if (t < 256) {
            float s = 0.f;
#pragma unroll
            for (int r = 0; r < REP; ++r) s += aload(ws + OFF_STAT2 + r*256 + t);
            bn2raw[t] = s;
        }
        __syncthreads();
        if (t < DIM) {
            float mu = bn2raw[t]*invn;
            float var = fmaxf(bn2raw[DIM + t]*invn - mu*mu, 0.f);
            mu2l[t] = mu;
            rs2l[t] = rsqrtf(var + EPS);
        }
        __syncthreads();
        {   // normalize x3 in place (same-thread elements)
            int c = t & 127;
            float mu = mu2l[c], rs = rs2l[c], gg = g2[c], bb = b2v[c];
#pragma unroll
            for (int k = 0; k < 4; ++k) {
                int e = t + k*NTHR;
                float v = (aggL[e] - mu)*rs*gg + bb;
                aggL[e] = fmaxf(v, 0.f);
            }
        }
        __syncthreads();
        int cg = t & 63, rg = t >> 6;
        float acc[2][4];
#pragma unroll
        for (int a = 0; a < 2; ++a)
#pragma unroll
            for (int q = 0; q < 4; ++q) acc[a][q] = 0.f;
        for (int k0 = 0; k0 < DIM; k0 += 32) {
            for (int i = t; i < 8192; i += NTHR) {
                int kk2 = i & 31, col = i >> 5;
                wT[kk2*260 + col] = w1[col*DIM + k0 + kk2];
            }
            __syncthreads();
#pragma unroll
            for (int q4 = 0; q4 < 8; ++q4) {
                float4 av[2], wv[4];
#pragma unroll
                for (int rr = 0; rr < 2; ++rr)
                    av[rr] = *(const float4*)&aggL[(rg*2+rr)*DIM + k0 + q4*4]; // wave-broadcast
#pragma unroll
                for (int q = 0; q < 4; ++q)
                    wv[q] = *(const float4*)&wT[(q4*4+q)*260 + cg*4];
#pragma unroll
                for (int rr = 0; rr < 2; ++rr) {
                    acc[rr][0] += av[rr].x*wv[0].x + av[rr].y*wv[1].x + av[rr].z*wv[2].x + av[rr].w*wv[3].x;
                    acc[rr][1] += av[rr].x*wv[0].y + av[rr].y*wv[1].y + av[rr].z*wv[2].y + av[rr].w*wv[3].y;
                    acc[rr][2] += av[rr].x*wv[0].z + av[rr].y*wv[1].z + av[rr].z*wv[2].z + av[rr].w*wv[3].z;
                    acc[rr][3] += av[rr].x*wv[0].w + av[rr].y*wv[1].w + av[rr].z*wv[2].w + av[rr].w*wv[3].w;
                }
            }
            __syncthreads();
        }
        int cbase = cg*4;
        float4 bv = *(const float4*)&b1v[cbase];
        float lv[4]  = {0,0,0,0};
        float lv2[4] = {0,0,0,0};
#pragma unroll
        for (int rr = 0; rr < 2; ++rr) {
            int row = rg*2 + rr;
            float o0 = acc[rr][0] + bv.x;
            float o1v = acc[rr][1] + bv.y;
            float o2 = acc[rr][2] + bv.z;
            float o3 = acc[rr][3] + bv.w;
            *(float4*)&o1L[row*INTER + cbase] = make_float4(o0, o1v, o2, o3);
            lv[0]+=o0;  lv2[0]+=o0*o0;
            lv[1]+=o1v; lv2[1]+=o1v*o1v;
            lv[2]+=o2;  lv2[2]+=o2*o2;
            lv[3]+=o3;  lv2[3]+=o3*o3;
        }
        *(float4*)&ps[rg*256 + cbase]  = make_float4(lv[0], lv[1], lv[2], lv[3]);
        *(float4*)&ps2[rg*256 + cbase] = make_float4(lv2[0], lv2[1], lv2[2], lv2[3]);
        __syncthreads();
        if (t < INTER) {
            float s1 = 0.f, s2 = 0.f;
#pragma unroll
            for (int q = 0; q < 8; ++q) { s1 += ps[q*256 + t]; s2 += ps2[q*256 + t]; }
            atomicAdd(&ws[OFF_STAT3 + (b & (REP-1))*512 + t], s1);
            atomicAdd(&ws[OFF_STAT3 + (b & (REP-1))*512 + INTER + t], s2);
        }
    }
    gbar(bar + 2*BAR_STRIDE);

    // ================= phase D: out = relu(bn3(o1)) @ w2^T + b2 ============
    {
        float* raw  = smem;          // 512
        float* mu3l = smem + 512;    // 256
        float* rs3l = smem + 768;    // 256
        float* o1L  = smem + R2_OFF; // [16][256]
        {
            float s = 0.f;
#pragma unroll
            for (int r = 0; r < REP; ++r) s += aload(ws + OFF_STAT3 + r*512 + t);
            raw[t] = s;
        }
        __syncthreads();
        if (t < INTER) {
            float mu = raw[t]*invn;
            float var = fmaxf(raw[256 + t]*invn - mu*mu, 0.f);
            mu3l[t] = mu;
            rs3l[t] = rsqrtf(var + EPS);
        }
        __syncthreads();
        float m3[4], rg3[4], b3q[4], w2q[4];
#pragma unroll
        for (int q = 0; q < 4; ++q) {
            int c = l*4 + q;
            m3[q] = mu3l[c];
            rg3[q] = rs3l[c]*g3[c];
            b3q[q] = b3[c];
            w2q[q] = w2[c];
        }
        float bias2 = b2s[0];
#pragma unroll
        for (int j = 0; j < 2; ++j) {
            int row = w*2 + j;
            float4 vv = *(const float4*)&o1L[row*INTER + l*4];
            float s = 0.f;
#pragma unroll
            for (int q = 0; q < 4; ++q) {
                float val = (((const float*)&vv)[q] - m3[q])*rg3[q] + b3q[q];
                val = fmaxf(val, 0.f);
                s += val * w2q[q];
            }
#pragma unroll
            for (int m = 32; m >= 1; m >>= 1) s += __shfl_xor(s, m, 64);
            if (l == 0) out[r0 + row] = s + bias2;
        }
    }
}

extern "C" void kernel_launch(void* const* d_in, const int* in_sizes, int n_in,
                              void* d_out, int out_size, void* d_ws, size_t ws_size,
                              hipStream_t stream) {
    const float* x        = (const float*)d_in[0];
    const float* emb      = (const float*)d_in[1];
    const float* w_lin    = (const float*)d_in[2];
    const float* att_i    = (const float*)d_in[3];
    const float* att_j    = (const float*)d_in[4];
    const float* att_em_i = (const float*)d_in[5];
    const float* att_em_j = (const float*)d_in[6];
    const float* g_bias   = (const float*)d_in[7];
    const float* bn1_g    = (const float*)d_in[8];
    const float* bn1_b    = (const float*)d_in[9];
    const float* bn2_g    = (const float*)d_in[10];
    const float* bn2_b    = (const float*)d_in[11];
    const float* bn3_g    = (const float*)d_in[12];
    const float* bn3_b    = (const float*)d_in[13];
    const float* w1       = (const float*)d_in[14];
    const float* b1       = (const float*)d_in[15];
    const float* w2       = (const float*)d_in[16];
    const float* b2       = (const float*)d_in[17];
    float* out = (float*)d_out;
    float* ws  = (float*)d_ws;

    hipMemsetAsync(d_ws, 0, ZERO_BYTES, stream);

    k_fused<<<NBLK, NTHR, 0, stream>>>(x, emb, w_lin, att_i, att_j, att_em_i,
                                       att_em_j, g_bias, bn1_g, bn1_b, bn2_g, bn2_b,
                                       bn3_g, bn3_b, w1, b1, w2, b2, ws, out);
}